// Round 2
// baseline (727.109 us; speedup 1.0000x reference)
//
#include <hip/hip_runtime.h>
#include <hip/hip_bf16.h>
#include <math.h>

// Problem constants (B=8, S=4096, H=1024, E=64, Hh=512)
#define N_TOK 32768
#define HDIM 1024
#define HH 512
#define NOUT 576   // 512 h-cols + 64 router cols
#define BM 256
#define BN 64
#define BK 32
#define THREADS 256
// OpenBLAS sgemm k-panel size (Haswell/Zen SGEMM_DEFAULT_Q)
#define KC 384

// Output layout in d_out (all float32):
#define OFF_SELW 0
#define OFF_SELI 262144
#define OFF_CONF 524288
#define OFF_LOG  557056

// Static device scratch
__device__ float  g_Bmat[HDIM * NOUT];      // fused [k][j] fp32 (W1^T | Wr^T)
__device__ double g_partial[N_TOK * 8];     // per-token per-h-tile fp64 partials

// ---------------- kernel 0: build fused B matrix ----------------
__global__ __launch_bounds__(256) void k_build(const float* __restrict__ W1,
                                               const float* __restrict__ Wr) {
  int idx = blockIdx.x * 256 + threadIdx.x;   // < HDIM*NOUT = 589824 exactly
  int k = idx / NOUT;
  int j = idx - k * NOUT;
  float v = (j < HH) ? W1[(size_t)j * HDIM + k] : Wr[(size_t)(j - HH) * HDIM + k];
  g_Bmat[idx] = v;
}

// ---------------- kernel 1: fused GEMM, OpenBLAS-faithful fp32 ----------------
// Per output element: fp32 fmaf chain, k ascending, blocked in panels of KC=384:
//   res = ((P0 + P1) + P2), Pi = sequential fmaf chain from 0 over its k-range.
// Reduction order per element is IDENTICAL to the previous passing kernel.
// New schedule: 256x64 block tile, 8x8 register tile per thread (64 FMA/kk),
// double-buffered LDS with ONE barrier per K-step; next tile's global loads
// issued before the compute phase (latency hidden under 4096 FMA-issue cycles).
__global__ __launch_bounds__(THREADS, 2) void k_gemm(const float* __restrict__ A,
                                                     const float* __restrict__ b1,
                                                     const float* __restrict__ W2,
                                                     const float* __restrict__ b_router,
                                                     float* __restrict__ out_logits) {
  __shared__ float As[2][BK][BM];   // 64 KB, transposed: As[buf][k][m]
  __shared__ float Bs[2][BK][BN];   // 16 KB

  // XCD swizzle: 9 n-tiles of one token-tile share blockIdx%8 -> same XCD L2
  int bid = blockIdx.x;          // 0..1151
  int xcd = bid & 7;
  int s   = bid >> 3;            // 0..143
  int j   = s % 9;               // n-tile 0..8
  int t   = xcd + 8 * (s / 9);   // token-tile 0..127

  const int tid = threadIdx.x;
  const int tx  = tid & 7;       // col group (8 cols)
  const int ty  = tid >> 3;      // row group (8 rows), 0..31
  const int m0  = t * BM;
  const int n0  = j * BN;

  float acc[8][8];    // current-panel chain
  float carry[8][8];  // folded previous panels (doubles as res at the end)
  #pragma unroll
  for (int i = 0; i < 8; ++i)
    #pragma unroll
    for (int c = 0; c < 8; ++c) { acc[i][c] = 0.f; carry[i][c] = 0.f; }

  // A staging: thread tid owns row tid of the 256-row tile; 8 float4 along k.
  const float* Ag = A + (size_t)(m0 + tid) * HDIM;

  float4 av[8];   // in-flight A staging (32 floats)
  float4 bv[2];   // in-flight B staging (8 floats)

  // ---- prologue: stage tile k0=0
  #pragma unroll
  for (int c = 0; c < 8; ++c) av[c] = *(const float4*)(Ag + c * 4);
  #pragma unroll
  for (int c = 0; c < 2; ++c) {
    int g  = tid + c * 256;
    int kr = g >> 4;             // 0..31
    int ch = g & 15;             // 0..15
    bv[c] = *(const float4*)&g_Bmat[(size_t)kr * NOUT + n0 + ch * 4];
  }
  #pragma unroll
  for (int c = 0; c < 8; ++c) {
    int kb = c * 4;
    As[0][kb + 0][tid] = av[c].x;
    As[0][kb + 1][tid] = av[c].y;
    As[0][kb + 2][tid] = av[c].z;
    As[0][kb + 3][tid] = av[c].w;
  }
  #pragma unroll
  for (int c = 0; c < 2; ++c) {
    int g  = tid + c * 256;
    int kr = g >> 4;
    int ch = g & 15;
    *(float4*)&Bs[0][kr][ch * 4] = bv[c];
  }
  __syncthreads();

  int p = 0;
  for (int k0 = 0; k0 < HDIM; k0 += BK) {
    const bool not_last = (k0 + BK < HDIM);

    // issue next tile's global loads NOW; consumed after compute
    if (not_last) {
      #pragma unroll
      for (int c = 0; c < 8; ++c) av[c] = *(const float4*)(Ag + (k0 + BK) + c * 4);
      #pragma unroll
      for (int c = 0; c < 2; ++c) {
        int g  = tid + c * 256;
        int kr = g >> 4;
        int ch = g & 15;
        bv[c] = *(const float4*)&g_Bmat[(size_t)(k0 + BK + kr) * NOUT + n0 + ch * 4];
      }
    }

    // panel fold at OpenBLAS KC boundaries (384, 768) -- uniform branch
    if (k0 == KC || k0 == 2 * KC) {
      #pragma unroll
      for (int i = 0; i < 8; ++i)
        #pragma unroll
        for (int c = 0; c < 8; ++c) {
          carry[i][c] = carry[i][c] + acc[i][c];  // plain fp32 add
          acc[i][c] = 0.f;
        }
    }

    // sequential-k fmaf chains (single accumulator per element, k ascending)
    #pragma unroll 2
    for (int kk = 0; kk < BK; ++kk) {
      float4 a03 = *(const float4*)&As[p][kk][ty * 8 + 0];
      float4 a47 = *(const float4*)&As[p][kk][ty * 8 + 4];
      float4 b03 = *(const float4*)&Bs[p][kk][tx * 8 + 0];
      float4 b47 = *(const float4*)&Bs[p][kk][tx * 8 + 4];
      float a[8] = {a03.x, a03.y, a03.z, a03.w, a47.x, a47.y, a47.z, a47.w};
      float b[8] = {b03.x, b03.y, b03.z, b03.w, b47.x, b47.y, b47.z, b47.w};
      #pragma unroll
      for (int i = 0; i < 8; ++i)
        #pragma unroll
        for (int c = 0; c < 8; ++c)
          acc[i][c] = fmaf(a[i], b[c], acc[i][c]);
    }

    // stage next tile into the other buffer; ONE barrier per K-step.
    // Safe: buf[p^1] was last read in the previous iteration, before the
    // previous barrier; every wave computing now reads only buf[p].
    if (not_last) {
      #pragma unroll
      for (int c = 0; c < 8; ++c) {
        int kb = c * 4;
        As[p ^ 1][kb + 0][tid] = av[c].x;
        As[p ^ 1][kb + 1][tid] = av[c].y;
        As[p ^ 1][kb + 2][tid] = av[c].z;
        As[p ^ 1][kb + 3][tid] = av[c].w;
      }
      #pragma unroll
      for (int c = 0; c < 2; ++c) {
        int g  = tid + c * 256;
        int kr = g >> 4;
        int ch = g & 15;
        *(float4*)&Bs[p ^ 1][kr][ch * 4] = bv[c];
      }
      __syncthreads();
      p ^= 1;
    }
  }

  // combine final panel: res = (P0+P1) + P2   (reuse carry as res)
  #pragma unroll
  for (int i = 0; i < 8; ++i)
    #pragma unroll
    for (int c = 0; c < 8; ++c) carry[i][c] = carry[i][c] + acc[i][c];

  // ---- epilogue
  if (j < 8) {
    double w2v[8];
    float  b1v[8];
    #pragma unroll
    for (int c = 0; c < 8; ++c) {
      w2v[c] = (double)W2[n0 + tx * 8 + c];
      b1v[c] = b1[n0 + tx * 8 + c];
    }
    #pragma unroll
    for (int i = 0; i < 8; ++i) {
      double sacc = 0.0;
      #pragma unroll
      for (int c = 0; c < 8; ++c) {
        // h in fp32 exactly as np: (matmul + b1) then relu
        float h = fmaxf(carry[i][c] + b1v[c], 0.f);
        sacc = fma((double)h, w2v[c], sacc);
      }
      // reduce across the 8 col-groups (lanes tx = lane&7)
      sacc += __shfl_xor(sacc, 1, 64);
      sacc += __shfl_xor(sacc, 2, 64);
      sacc += __shfl_xor(sacc, 4, 64);
      if (tx == 0) g_partial[(size_t)(m0 + ty * 8 + i) * 8 + j] = sacc;
    }
  } else {
    float brv[8];
    #pragma unroll
    for (int c = 0; c < 8; ++c) brv[c] = b_router[tx * 8 + c];
    #pragma unroll
    for (int i = 0; i < 8; ++i) {
      int row = m0 + ty * 8 + i;
      float o[8];
      #pragma unroll
      for (int c = 0; c < 8; ++c) o[c] = carry[i][c] + brv[c];  // fp32 bias add
      *(float4*)&out_logits[(size_t)row * 64 + tx * 8 + 0] =
          make_float4(o[0], o[1], o[2], o[3]);
      *(float4*)&out_logits[(size_t)row * 64 + tx * 8 + 4] =
          make_float4(o[4], o[5], o[6], o[7]);
    }
  }
}

// ---------------- kernel 2: per-token postlude, 8 lanes per token ----------------
// Wave = 64 lanes = 8 tokens x 8 lanes. Lane q of a token owns experts
// {q, q+8, ..., q+56} -- exactly the numpy pairwise-8 accumulator lanes, so the
// in-lane ascending-b sum + 3-step shfl_xor tree reproduces
// ((r0+r1)+(r2+r3))+((r4+r5)+(r6+r7)) bit-exactly. Max is associative ->
// tree == sequential. expf / true division unchanged -> identical bits.
// Top-8: per-lane strict-> scan + 3-step shfl argmax with tie -> lowest global
// index: equivalent to the sequential lowest-index-on-tie scan.
// Confidence in fp64 (tree order; fp64 noise ~1e-16 << ref fp32 noise ~3e-7).
__global__ __launch_bounds__(256) void k_post(const float* __restrict__ b2,
                                              float* __restrict__ d_out) {
  const int lane = threadIdx.x & 63;
  const int wave = threadIdx.x >> 6;       // 0..3
  const int q    = lane & 7;               // lane-within-token
  const int tsub = lane >> 3;              // token-within-wave 0..7
  const int tk   = blockIdx.x * 32 + wave * 8 + tsub;   // < 32768

  // ---- confidence: fp64 tree-sum of the 8 tile partials (coalesced read) ----
  double p = g_partial[(size_t)tk * 8 + q];
  p += __shfl_xor(p, 1, 64);
  p += __shfl_xor(p, 2, 64);
  p += __shfl_xor(p, 4, 64);
  double ca   = (double)b2[0] + p;
  double conf = 1.0 / (1.0 + exp(-ca));
  double dkf  = 1.0 + 7.0 * (1.0 - conf);
  double dkr  = rint(dkf);                 // round half-to-even == jnp.round
  int dk = (int)fmin(fmax(dkr, 1.0), 8.0);

  // ---- logits: lane q loads experts b*8+q (stride-8, L1/L2-resident row) ----
  const float* logits = d_out + OFF_LOG + (size_t)tk * 64;
  float l[8];
  #pragma unroll
  for (int b = 0; b < 8; ++b) l[b] = logits[b * 8 + q];

  // max over 64 (associative -> any order bit-identical)
  float mx = l[0];
  #pragma unroll
  for (int b = 1; b < 8; ++b) mx = fmaxf(mx, l[b]);
  mx = fmaxf(mx, __shfl_xor(mx, 1, 64));
  mx = fmaxf(mx, __shfl_xor(mx, 2, 64));
  mx = fmaxf(mx, __shfl_xor(mx, 4, 64));

  float ex[8];
  #pragma unroll
  for (int b = 0; b < 8; ++b) ex[b] = expf(l[b] - mx);

  // numpy pairwise-8 base case: r[q] = ex[q] + ex[8+q] + ... (b ascending)
  float r = ex[0];
  #pragma unroll
  for (int b = 1; b < 8; ++b) r += ex[b];
  // ((r0+r1)+(r2+r3)) + ((r4+r5)+(r6+r7)) via commutative xor-tree
  r += __shfl_xor(r, 1, 64);
  r += __shfl_xor(r, 2, 64);
  float ssum = r + __shfl_xor(r, 4, 64);

  float v[8];
  #pragma unroll
  for (int b = 0; b < 8; ++b) v[b] = ex[b] / ssum;   // true IEEE division

  // ---- stable top-8 (strict >, ties keep lowest global expert index) ----
  float myw = 0.f, myi = 0.f;      // lane q records slot q's outputs
  unsigned used = 0u;
  #pragma unroll
  for (int slot = 0; slot < 8; ++slot) {
    float best = -1.f;
    int   bi   = 64;               // sentinel, never survives (all v > -1)
    #pragma unroll
    for (int b = 0; b < 8; ++b) {
      bool ok = (((used >> b) & 1u) == 0u) && (v[b] > best);
      best = ok ? v[b] : best;
      bi   = ok ? (b * 8 + q) : bi;
    }
    #pragma unroll
    for (int m = 1; m <= 4; m <<= 1) {
      float ow = __shfl_xor(best, m, 64);
      int   oi = __shfl_xor(bi,   m, 64);
      bool take = (ow > best) || (ow == best && oi < bi);
      best = take ? ow : best;
      bi   = take ? oi : bi;
    }
    if ((bi & 7) == q) used |= (1u << (bi >> 3));   // owning lane retires it
    bool active = slot < dk;
    if (slot == q) {
      myw = active ? best : 0.f;
      myi = active ? (float)bi : 0.f;
    }
  }

  // wave writes 64 consecutive floats: tokens x slots, fully coalesced
  d_out[OFF_SELW + (size_t)tk * 8 + q] = myw;
  d_out[OFF_SELI + (size_t)tk * 8 + q] = myi;
  if (q == 0) d_out[OFF_CONF + tk] = (float)conf;
}

extern "C" void kernel_launch(void* const* d_in, const int* in_sizes, int n_in,
                              void* d_out, int out_size, void* d_ws, size_t ws_size,
                              hipStream_t stream) {
  const float* hidden   = (const float*)d_in[0];
  const float* W_router = (const float*)d_in[1];
  const float* b_router = (const float*)d_in[2];
  const float* W1       = (const float*)d_in[3];
  const float* b1       = (const float*)d_in[4];
  const float* W2       = (const float*)d_in[5];
  const float* b2       = (const float*)d_in[6];
  float* out = (float*)d_out;

  k_build<<<(HDIM * NOUT) / 256, 256, 0, stream>>>(W1, W_router);
  k_gemm<<<(N_TOK / BM) * 9, THREADS, 0, stream>>>(hidden, b1, W2, b_router,
                                                   out + OFF_LOG);
  k_post<<<N_TOK / 32, 256, 0, stream>>>(b2, out);
}

// Round 4
// 707.088 us; speedup vs baseline: 1.0283x; 1.0283x over previous
//
#include <hip/hip_runtime.h>
#include <hip/hip_bf16.h>
#include <math.h>

// Problem constants (B=8, S=4096, H=1024, E=64, Hh=512)
#define N_TOK 32768
#define HDIM 1024
#define HH 512
#define NOUT 576   // 512 h-cols + 64 router cols
#define BM 128
#define BN 64
#define BK 32
#define THREADS 128
// OpenBLAS sgemm k-panel size (Haswell/Zen SGEMM_DEFAULT_Q)
#define KC 384

// Output layout in d_out (all float32):
#define OFF_SELW 0
#define OFF_SELI 262144
#define OFF_CONF 524288
#define OFF_LOG  557056

// Static device scratch
__device__ __align__(16) float  g_Bmat[HDIM * NOUT];  // fused [k][j] fp32 (W1^T | Wr^T)
__device__ double g_partial[N_TOK * 8];               // per-token per-h-tile fp64 partials

// ---------------- kernel 0: build fused B matrix ----------------
__global__ __launch_bounds__(256) void k_build(const float* __restrict__ W1,
                                               const float* __restrict__ Wr) {
  int idx = blockIdx.x * 256 + threadIdx.x;   // < HDIM*NOUT = 589824 exactly
  int k = idx / NOUT;
  int j = idx - k * NOUT;
  float v = (j < HH) ? W1[(size_t)j * HDIM + k] : Wr[(size_t)(j - HH) * HDIM + k];
  g_Bmat[idx] = v;
}

// async global->LDS, 16B per lane; LDS dest is wave-uniform base + lane*16 (HW)
__device__ __forceinline__ void gl_lds16(const float* g, float* l) {
  __builtin_amdgcn_global_load_lds(
      (const __attribute__((address_space(1))) void*)g,
      (__attribute__((address_space(3))) void*)l, 16, 0, 0);
}

// ---------------- kernel 1: fused GEMM, OpenBLAS-faithful fp32 ----------------
// Per output element: fp32 fmaf chain, k ascending, blocked in panels of KC=384:
//   res = ((P0 + P1) + P2), Pi = sequential fmaf chain from 0 over its k-range.
// Reduction order per element IDENTICAL to all previous passing kernels.
// Schedule: 128x64 tile, 8x8 register tile (64 FMA/kk), double-buffered LDS
// staged via global_load_lds (zero staging VGPRs / LDS-write instrs), ONE
// barrier per K-step; next tile's loads issued before the 4096-cycle compute.
// A stored row-major [m][32] with XOR chunk-swizzle keyed on (m>>3)&7:
// swizzle applied to the GLOBAL source address (LDS dest stays linear, as
// global_load_lds requires) and inverted on the ds_read -> conflict-free.
__global__ __launch_bounds__(THREADS, 2) void k_gemm(const float* __restrict__ A,
                                                     const float* __restrict__ b1,
                                                     const float* __restrict__ W2,
                                                     const float* __restrict__ b_router,
                                                     float* __restrict__ out_logits) {
  __shared__ __align__(16) float As[2][BM][BK];   // 32 KB total, swizzled content
  __shared__ __align__(16) float Bs[2][BK][BN];   // 16 KB total, linear [k][n]

  // XCD swizzle: 9 n-tiles of one token-tile share blockIdx%8 -> same XCD L2
  int bid = blockIdx.x;          // 0..2303
  int xcd = bid & 7;
  int s   = bid >> 3;            // 0..287
  int j   = s % 9;               // n-tile 0..8
  int t   = xcd + 8 * (s / 9);   // token-tile 0..255

  const int tid  = threadIdx.x;  // 0..127
  const int lane = tid & 63;
  const int w    = tid >> 6;     // wave 0/1
  const int tx   = tid & 7;      // col group (8 cols)
  const int ty   = tid >> 3;     // row group (8 rows), 0..15
  const int ty7  = ty & 7;       // swizzle key for this thread's rows
  const int m0   = t * BM;
  const int n0   = j * BN;

  // lane-constant staging address parts
  const int a_r  = lane >> 3;          // row within 8-row segment
  const int a_c4 = (lane & 7) * 4;     // k-chunk*4 floats (pre-XOR)
  const int b_r  = lane >> 4;          // k-row within 4-row segment
  const int b_c4 = (lane & 15) * 4;    // n-offset floats

  float acc[8][8];    // current-panel chain
  float carry[8][8];  // folded previous panels (doubles as res at the end)
  #pragma unroll
  for (int i = 0; i < 8; ++i)
    #pragma unroll
    for (int c = 0; c < 8; ++c) { acc[i][c] = 0.f; carry[i][c] = 0.f; }

  // stage one K-tile into buffer pb: 12 global_load_lds per wave, async
  auto stage = [&](int pb, int k0) {
    #pragma unroll
    for (int ci = 0; ci < 8; ++ci) {           // A: 16 segs of 256 floats
      int sg = w * 8 + ci;
      const float* src = A + (size_t)(m0 + sg * 8 + a_r) * HDIM + k0 +
                         (a_c4 ^ ((sg & 7) * 4));   // pre-swizzled source
      gl_lds16(src, &As[pb][0][0] + sg * 256);
    }
    #pragma unroll
    for (int ci = 0; ci < 4; ++ci) {           // B: 8 segs of 256 floats
      int sg = w * 4 + ci;
      const float* src = g_Bmat + (size_t)(k0 + sg * 4 + b_r) * NOUT + n0 + b_c4;
      gl_lds16(src, &Bs[pb][0][0] + sg * 256);
    }
  };

  // ---- prologue: stage tile k0=0
  stage(0, 0);
  __syncthreads();   // compiler drains vmcnt before s_barrier

  int p = 0;
  for (int k0 = 0; k0 < HDIM; k0 += BK) {
    // issue next tile's loads NOW; latency hides under the 2048-FMA compute
    if (k0 + BK < HDIM) stage(p ^ 1, k0 + BK);

    // panel fold at OpenBLAS KC boundaries (384, 768) -- uniform branch
    if (k0 == KC || k0 == 2 * KC) {
      #pragma unroll
      for (int i = 0; i < 8; ++i)
        #pragma unroll
        for (int c = 0; c < 8; ++c) {
          carry[i][c] = carry[i][c] + acc[i][c];  // plain fp32 add
          acc[i][c] = 0.f;
        }
    }

    // sequential-k fmaf chains; k = kk4*4+d ascends 0..31 within the tile
    #pragma unroll 2
    for (int kk4 = 0; kk4 < 8; ++kk4) {
      float4 af[8];
      #pragma unroll
      for (int i = 0; i < 8; ++i)   // swizzled read: chunk kk4 ^ ty7
        af[i] = *(const float4*)&As[p][ty * 8 + i][(kk4 ^ ty7) * 4];
      #pragma unroll
      for (int d = 0; d < 4; ++d) {
        float4 b03 = *(const float4*)&Bs[p][kk4 * 4 + d][tx * 8 + 0];
        float4 b47 = *(const float4*)&Bs[p][kk4 * 4 + d][tx * 8 + 4];
        float bb[8] = {b03.x, b03.y, b03.z, b03.w, b47.x, b47.y, b47.z, b47.w};
        float aa[8];
        #pragma unroll
        for (int i = 0; i < 8; ++i)
          aa[i] = (d == 0) ? af[i].x : (d == 1) ? af[i].y
                : (d == 2) ? af[i].z : af[i].w;
        #pragma unroll
        for (int i = 0; i < 8; ++i)
          #pragma unroll
          for (int c = 0; c < 8; ++c)
            acc[i][c] = fmaf(aa[i], bb[c], acc[i][c]);
      }
    }

    __syncthreads();   // one barrier per K-step: drains staging vmcnt + LDS
    p ^= 1;
  }

  // combine final panel: res = (P0+P1) + P2   (reuse carry as res)
  #pragma unroll
  for (int i = 0; i < 8; ++i)
    #pragma unroll
    for (int c = 0; c < 8; ++c) carry[i][c] = carry[i][c] + acc[i][c];

  // ---- epilogue (identical numerics to previous passing kernel)
  if (j < 8) {
    double w2v[8];
    float  b1v[8];
    #pragma unroll
    for (int c = 0; c < 8; ++c) {
      w2v[c] = (double)W2[n0 + tx * 8 + c];
      b1v[c] = b1[n0 + tx * 8 + c];
    }
    #pragma unroll
    for (int i = 0; i < 8; ++i) {
      double sacc = 0.0;
      #pragma unroll
      for (int c = 0; c < 8; ++c) {
        // h in fp32 exactly as np: (matmul + b1) then relu
        float h = fmaxf(carry[i][c] + b1v[c], 0.f);
        sacc = fma((double)h, w2v[c], sacc);
      }
      // reduce across the 8 col-groups (lanes tx = lane&7)
      sacc += __shfl_xor(sacc, 1, 64);
      sacc += __shfl_xor(sacc, 2, 64);
      sacc += __shfl_xor(sacc, 4, 64);
      if (tx == 0) g_partial[(size_t)(m0 + ty * 8 + i) * 8 + j] = sacc;
    }
  } else {
    float brv[8];
    #pragma unroll
    for (int c = 0; c < 8; ++c) brv[c] = b_router[tx * 8 + c];
    #pragma unroll
    for (int i = 0; i < 8; ++i) {
      int row = m0 + ty * 8 + i;
      float o[8];
      #pragma unroll
      for (int c = 0; c < 8; ++c) o[c] = carry[i][c] + brv[c];  // fp32 bias add
      *(float4*)&out_logits[(size_t)row * 64 + tx * 8 + 0] =
          make_float4(o[0], o[1], o[2], o[3]);
      *(float4*)&out_logits[(size_t)row * 64 + tx * 8 + 4] =
          make_float4(o[4], o[5], o[6], o[7]);
    }
  }
}

// ---------------- kernel 2: per-token postlude, 8 lanes per token ----------------
// Wave = 64 lanes = 8 tokens x 8 lanes. Lane q of a token owns experts
// {q, q+8, ..., q+56} -- exactly the numpy pairwise-8 accumulator lanes, so the
// in-lane ascending-b sum + 3-step shfl_xor tree reproduces
// ((r0+r1)+(r2+r3))+((r4+r5)+(r6+r7)) bit-exactly. Max is associative ->
// tree == sequential. expf / true division unchanged -> identical bits.
// Top-8: per-lane strict-> scan + 3-step shfl argmax with tie -> lowest global
// index: equivalent to the sequential lowest-index-on-tie scan.
// Confidence in fp64 (tree order; fp64 noise ~1e-16 << ref fp32 noise ~3e-7).
__global__ __launch_bounds__(256) void k_post(const float* __restrict__ b2,
                                              float* __restrict__ d_out) {
  const int lane = threadIdx.x & 63;
  const int wave = threadIdx.x >> 6;       // 0..3
  const int q    = lane & 7;               // lane-within-token
  const int tsub = lane >> 3;              // token-within-wave 0..7
  const int tk   = blockIdx.x * 32 + wave * 8 + tsub;   // < 32768

  // ---- confidence: fp64 tree-sum of the 8 tile partials (coalesced read) ----
  double p = g_partial[(size_t)tk * 8 + q];
  p += __shfl_xor(p, 1, 64);
  p += __shfl_xor(p, 2, 64);
  p += __shfl_xor(p, 4, 64);
  double ca   = (double)b2[0] + p;
  double conf = 1.0 / (1.0 + exp(-ca));
  double dkf  = 1.0 + 7.0 * (1.0 - conf);
  double dkr  = rint(dkf);                 // round half-to-even == jnp.round
  int dk = (int)fmin(fmax(dkr, 1.0), 8.0);

  // ---- logits: lane q loads experts b*8+q (stride-8, L1/L2-resident row) ----
  const float* logits = d_out + OFF_LOG + (size_t)tk * 64;
  float l[8];
  #pragma unroll
  for (int b = 0; b < 8; ++b) l[b] = logits[b * 8 + q];

  // max over 64 (associative -> any order bit-identical)
  float mx = l[0];
  #pragma unroll
  for (int b = 1; b < 8; ++b) mx = fmaxf(mx, l[b]);
  mx = fmaxf(mx, __shfl_xor(mx, 1, 64));
  mx = fmaxf(mx, __shfl_xor(mx, 2, 64));
  mx = fmaxf(mx, __shfl_xor(mx, 4, 64));

  float ex[8];
  #pragma unroll
  for (int b = 0; b < 8; ++b) ex[b] = expf(l[b] - mx);

  // numpy pairwise-8 base case: r[q] = ex[q] + ex[8+q] + ... (b ascending)
  float r = ex[0];
  #pragma unroll
  for (int b = 1; b < 8; ++b) r += ex[b];
  // ((r0+r1)+(r2+r3)) + ((r4+r5)+(r6+r7)) via commutative xor-tree
  r += __shfl_xor(r, 1, 64);
  r += __shfl_xor(r, 2, 64);
  float ssum = r + __shfl_xor(r, 4, 64);

  float v[8];
  #pragma unroll
  for (int b = 0; b < 8; ++b) v[b] = ex[b] / ssum;   // true IEEE division

  // ---- stable top-8 (strict >, ties keep lowest global expert index) ----
  float myw = 0.f, myi = 0.f;      // lane q records slot q's outputs
  unsigned used = 0u;
  #pragma unroll
  for (int slot = 0; slot < 8; ++slot) {
    float best = -1.f;
    int   bi   = 64;               // sentinel, never survives (all v > -1)
    #pragma unroll
    for (int b = 0; b < 8; ++b) {
      bool ok = (((used >> b) & 1u) == 0u) && (v[b] > best);
      best = ok ? v[b] : best;
      bi   = ok ? (b * 8 + q) : bi;
    }
    #pragma unroll
    for (int m = 1; m <= 4; m <<= 1) {
      float ow = __shfl_xor(best, m, 64);
      int   oi = __shfl_xor(bi,   m, 64);
      bool take = (ow > best) || (ow == best && oi < bi);
      best = take ? ow : best;
      bi   = take ? oi : bi;
    }
    if ((bi & 7) == q) used |= (1u << (bi >> 3));   // owning lane retires it
    bool active = slot < dk;
    if (slot == q) {
      myw = active ? best : 0.f;
      myi = active ? (float)bi : 0.f;
    }
  }

  // wave writes 64 consecutive floats: tokens x slots, fully coalesced
  d_out[OFF_SELW + (size_t)tk * 8 + q] = myw;
  d_out[OFF_SELI + (size_t)tk * 8 + q] = myi;
  if (q == 0) d_out[OFF_CONF + tk] = (float)conf;
}

extern "C" void kernel_launch(void* const* d_in, const int* in_sizes, int n_in,
                              void* d_out, int out_size, void* d_ws, size_t ws_size,
                              hipStream_t stream) {
  const float* hidden   = (const float*)d_in[0];
  const float* W_router = (const float*)d_in[1];
  const float* b_router = (const float*)d_in[2];
  const float* W1       = (const float*)d_in[3];
  const float* b1       = (const float*)d_in[4];
  const float* W2       = (const float*)d_in[5];
  const float* b2       = (const float*)d_in[6];
  float* out = (float*)d_out;

  k_build<<<(HDIM * NOUT) / 256, 256, 0, stream>>>(W1, W_router);
  k_gemm<<<(N_TOK / BM) * 9, THREADS, 0, stream>>>(hidden, b1, W2, b_router,
                                                   out + OFF_LOG);
  k_post<<<N_TOK / 32, 256, 0, stream>>>(b2, out);
}

// Round 5
// 647.555 us; speedup vs baseline: 1.1229x; 1.0919x over previous
//
#include <hip/hip_runtime.h>
#include <hip/hip_bf16.h>
#include <math.h>

// Problem constants (B=8, S=4096, H=1024, E=64, Hh=512)
#define N_TOK 32768
#define HDIM 1024
#define HH 512
#define NOUT 576   // 512 h-cols + 64 router cols
#define BM 128
#define BN 64
#define BK 32
#define THREADS 256
// OpenBLAS sgemm k-panel size (Haswell/Zen SGEMM_DEFAULT_Q)
#define KC 384

// Output layout in d_out (all float32):
#define OFF_SELW 0
#define OFF_SELI 262144
#define OFF_CONF 524288
#define OFF_LOG  557056

// Static device scratch
__device__ __align__(16) float  g_Bmat[HDIM * NOUT];  // fused [k][j] fp32 (W1^T | Wr^T)
__device__ double g_partial[N_TOK * 8];               // per-token per-h-tile fp64 partials

// ---------------- kernel 0: build fused B matrix ----------------
__global__ __launch_bounds__(256) void k_build(const float* __restrict__ W1,
                                               const float* __restrict__ Wr) {
  int idx = blockIdx.x * 256 + threadIdx.x;   // < HDIM*NOUT = 589824 exactly
  int k = idx / NOUT;
  int j = idx - k * NOUT;
  float v = (j < HH) ? W1[(size_t)j * HDIM + k] : Wr[(size_t)(j - HH) * HDIM + k];
  g_Bmat[idx] = v;
}

// async global->LDS, 16B per lane; LDS dest is wave-uniform base + lane*16 (HW)
__device__ __forceinline__ void gl_lds16(const float* g, float* l) {
  __builtin_amdgcn_global_load_lds(
      (const __attribute__((address_space(1))) void*)g,
      (__attribute__((address_space(3))) void*)l, 16, 0, 0);
}

// ---------------- kernel 1: fused GEMM, OpenBLAS-faithful fp32 ----------------
// Per output element: fp32 fmaf chain, k ascending, blocked in panels of KC=384:
//   res = ((P0 + P1) + P2), Pi = sequential fmaf chain from 0 over its k-range.
// Reduction order per element IDENTICAL to all previous passing kernels.
// Schedule: 128x64 tile, 256 threads, 4x8 register tile (32 FMA/kk),
// double-buffered LDS staged via global_load_lds (zero staging VGPRs), ONE
// barrier per K-step, next tile's loads issued before the compute phase.
// Occupancy: 48 KB LDS -> 3 blocks/CU x 4 waves = 12 waves/CU (3/SIMD), three
// independent barrier domains per CU so vmcnt drains overlap other blocks.
// A stored row-major [m][32] with XOR chunk-swizzle keyed on (m>>2)&7:
// swizzle applied to the GLOBAL source address (LDS dest stays linear, as
// global_load_lds requires) and inverted on the ds_read -> conflict-free
// (a wave's 8 row-groups carry 8 distinct keys -> 8 distinct bank quads).
__global__ __launch_bounds__(THREADS, 3) void k_gemm(const float* __restrict__ A,
                                                     const float* __restrict__ b1,
                                                     const float* __restrict__ W2,
                                                     const float* __restrict__ b_router,
                                                     float* __restrict__ out_logits) {
  __shared__ __align__(16) float As[2][BM][BK];   // 32 KB total, swizzled content
  __shared__ __align__(16) float Bs[2][BK][BN];   // 16 KB total, linear [k][n]

  // XCD swizzle: 9 n-tiles of one token-tile share blockIdx%8 -> same XCD L2
  int bid = blockIdx.x;          // 0..2303
  int xcd = bid & 7;
  int s   = bid >> 3;            // 0..287
  int j   = s % 9;               // n-tile 0..8
  int t   = xcd + 8 * (s / 9);   // token-tile 0..255

  const int tid  = threadIdx.x;  // 0..255
  const int lane = tid & 63;
  const int w    = tid >> 6;     // wave 0..3
  const int tx   = tid & 7;      // col group (8 cols)
  const int ty   = tid >> 3;     // row group (4 rows), 0..31
  const int ty7  = ty & 7;       // swizzle key for this thread's rows
  const int m0   = t * BM;
  const int n0   = j * BN;

  // lane-constant staging address parts
  const int a_r  = lane >> 3;          // row within 8-row segment (0..7)
  const int a_c4 = (lane & 7) * 4;     // k-chunk*4 floats (pre-XOR)
  const int b_r  = lane >> 4;          // k-row within 4-row segment (0..3)
  const int b_c4 = (lane & 15) * 4;    // n-offset floats

  float acc[4][8];    // current-panel chain
  float carry[4][8];  // folded previous panels (doubles as res at the end)
  #pragma unroll
  for (int i = 0; i < 4; ++i)
    #pragma unroll
    for (int c = 0; c < 8; ++c) { acc[i][c] = 0.f; carry[i][c] = 0.f; }

  // stage one K-tile into buffer pb: 6 global_load_lds per wave, async
  auto stage = [&](int pb, int k0) {
    #pragma unroll
    for (int ci = 0; ci < 4; ++ci) {           // A: 16 segs of 256 floats
      int sg  = w * 4 + ci;                    // 8 rows per segment
      int key = (sg * 2 + (a_r >> 2)) & 7;     // == ((m>>2)&7) for this row
      const float* src = A + (size_t)(m0 + sg * 8 + a_r) * HDIM + k0 +
                         (a_c4 ^ (key * 4));   // pre-swizzled source
      gl_lds16(src, &As[pb][0][0] + sg * 256);
    }
    #pragma unroll
    for (int ci = 0; ci < 2; ++ci) {           // B: 8 segs of 256 floats
      int sg = w * 2 + ci;
      const float* src = g_Bmat + (size_t)(k0 + sg * 4 + b_r) * NOUT + n0 + b_c4;
      gl_lds16(src, &Bs[pb][0][0] + sg * 256);
    }
  };

  // ---- prologue: stage tile k0=0
  stage(0, 0);
  __syncthreads();   // compiler drains vmcnt before s_barrier

  int p = 0;
  for (int k0 = 0; k0 < HDIM; k0 += BK) {
    // issue next tile's loads NOW; latency hides under the compute phase
    if (k0 + BK < HDIM) stage(p ^ 1, k0 + BK);

    // panel fold at OpenBLAS KC boundaries (384, 768) -- uniform branch
    if (k0 == KC || k0 == 2 * KC) {
      #pragma unroll
      for (int i = 0; i < 4; ++i)
        #pragma unroll
        for (int c = 0; c < 8; ++c) {
          carry[i][c] = carry[i][c] + acc[i][c];  // plain fp32 add
          acc[i][c] = 0.f;
        }
    }

    // sequential-k fmaf chains; k = kk4*4+d ascends 0..31 within the tile
    #pragma unroll 2
    for (int kk4 = 0; kk4 < 8; ++kk4) {
      float4 af[4];
      #pragma unroll
      for (int i = 0; i < 4; ++i)   // swizzled read: chunk kk4 ^ ty7
        af[i] = *(const float4*)&As[p][ty * 4 + i][(kk4 ^ ty7) * 4];
      #pragma unroll
      for (int d = 0; d < 4; ++d) {
        float4 b03 = *(const float4*)&Bs[p][kk4 * 4 + d][tx * 8 + 0];
        float4 b47 = *(const float4*)&Bs[p][kk4 * 4 + d][tx * 8 + 4];
        float bb[8] = {b03.x, b03.y, b03.z, b03.w, b47.x, b47.y, b47.z, b47.w};
        float aa[4];
        #pragma unroll
        for (int i = 0; i < 4; ++i)
          aa[i] = (d == 0) ? af[i].x : (d == 1) ? af[i].y
                : (d == 2) ? af[i].z : af[i].w;
        #pragma unroll
        for (int i = 0; i < 4; ++i)
          #pragma unroll
          for (int c = 0; c < 8; ++c)
            acc[i][c] = fmaf(aa[i], bb[c], acc[i][c]);
      }
    }

    __syncthreads();   // one barrier per K-step: drains staging vmcnt + LDS
    p ^= 1;
  }

  // combine final panel: res = (P0+P1) + P2   (reuse carry as res)
  #pragma unroll
  for (int i = 0; i < 4; ++i)
    #pragma unroll
    for (int c = 0; c < 8; ++c) carry[i][c] = carry[i][c] + acc[i][c];

  // ---- epilogue (identical numerics to previous passing kernels)
  if (j < 8) {
    double w2v[8];
    float  b1v[8];
    #pragma unroll
    for (int c = 0; c < 8; ++c) {
      w2v[c] = (double)W2[n0 + tx * 8 + c];
      b1v[c] = b1[n0 + tx * 8 + c];
    }
    #pragma unroll
    for (int i = 0; i < 4; ++i) {
      double sacc = 0.0;
      #pragma unroll
      for (int c = 0; c < 8; ++c) {
        // h in fp32 exactly as np: (matmul + b1) then relu
        float h = fmaxf(carry[i][c] + b1v[c], 0.f);
        sacc = fma((double)h, w2v[c], sacc);
      }
      // reduce across the 8 col-groups (lanes tx = lane&7)
      sacc += __shfl_xor(sacc, 1, 64);
      sacc += __shfl_xor(sacc, 2, 64);
      sacc += __shfl_xor(sacc, 4, 64);
      if (tx == 0) g_partial[(size_t)(m0 + ty * 4 + i) * 8 + j] = sacc;
    }
  } else {
    float brv[8];
    #pragma unroll
    for (int c = 0; c < 8; ++c) brv[c] = b_router[tx * 8 + c];
    #pragma unroll
    for (int i = 0; i < 4; ++i) {
      int row = m0 + ty * 4 + i;
      float o[8];
      #pragma unroll
      for (int c = 0; c < 8; ++c) o[c] = carry[i][c] + brv[c];  // fp32 bias add
      *(float4*)&out_logits[(size_t)row * 64 + tx * 8 + 0] =
          make_float4(o[0], o[1], o[2], o[3]);
      *(float4*)&out_logits[(size_t)row * 64 + tx * 8 + 4] =
          make_float4(o[4], o[5], o[6], o[7]);
    }
  }
}

// ---------------- kernel 2: per-token postlude, 8 lanes per token ----------------
// Wave = 64 lanes = 8 tokens x 8 lanes. Lane q of a token owns experts
// {q, q+8, ..., q+56} -- exactly the numpy pairwise-8 accumulator lanes, so the
// in-lane ascending-b sum + 3-step shfl_xor tree reproduces
// ((r0+r1)+(r2+r3))+((r4+r5)+(r6+r7)) bit-exactly. Max is associative ->
// tree == sequential. expf / true division unchanged -> identical bits.
// Top-8: per-lane strict-> scan + 3-step shfl argmax with tie -> lowest global
// index: equivalent to the sequential lowest-index-on-tie scan.
// Confidence in fp64 (tree order; fp64 noise ~1e-16 << ref fp32 noise ~3e-7).
__global__ __launch_bounds__(256) void k_post(const float* __restrict__ b2,
                                              float* __restrict__ d_out) {
  const int lane = threadIdx.x & 63;
  const int wave = threadIdx.x >> 6;       // 0..3
  const int q    = lane & 7;               // lane-within-token
  const int tsub = lane >> 3;              // token-within-wave 0..7
  const int tk   = blockIdx.x * 32 + wave * 8 + tsub;   // < 32768

  // ---- confidence: fp64 tree-sum of the 8 tile partials (coalesced read) ----
  double p = g_partial[(size_t)tk * 8 + q];
  p += __shfl_xor(p, 1, 64);
  p += __shfl_xor(p, 2, 64);
  p += __shfl_xor(p, 4, 64);
  double ca   = (double)b2[0] + p;
  double conf = 1.0 / (1.0 + exp(-ca));
  double dkf  = 1.0 + 7.0 * (1.0 - conf);
  double dkr  = rint(dkf);                 // round half-to-even == jnp.round
  int dk = (int)fmin(fmax(dkr, 1.0), 8.0);

  // ---- logits: lane q loads experts b*8+q (stride-8, L1/L2-resident row) ----
  const float* logits = d_out + OFF_LOG + (size_t)tk * 64;
  float l[8];
  #pragma unroll
  for (int b = 0; b < 8; ++b) l[b] = logits[b * 8 + q];

  // max over 64 (associative -> any order bit-identical)
  float mx = l[0];
  #pragma unroll
  for (int b = 1; b < 8; ++b) mx = fmaxf(mx, l[b]);
  mx = fmaxf(mx, __shfl_xor(mx, 1, 64));
  mx = fmaxf(mx, __shfl_xor(mx, 2, 64));
  mx = fmaxf(mx, __shfl_xor(mx, 4, 64));

  float ex[8];
  #pragma unroll
  for (int b = 0; b < 8; ++b) ex[b] = expf(l[b] - mx);

  // numpy pairwise-8 base case: r[q] = ex[q] + ex[8+q] + ... (b ascending)
  float r = ex[0];
  #pragma unroll
  for (int b = 1; b < 8; ++b) r += ex[b];
  // ((r0+r1)+(r2+r3)) + ((r4+r5)+(r6+r7)) via commutative xor-tree
  r += __shfl_xor(r, 1, 64);
  r += __shfl_xor(r, 2, 64);
  float ssum = r + __shfl_xor(r, 4, 64);

  float v[8];
  #pragma unroll
  for (int b = 0; b < 8; ++b) v[b] = ex[b] / ssum;   // true IEEE division

  // ---- stable top-8 (strict >, ties keep lowest global expert index) ----
  float myw = 0.f, myi = 0.f;      // lane q records slot q's outputs
  unsigned used = 0u;
  #pragma unroll
  for (int slot = 0; slot < 8; ++slot) {
    float best = -1.f;
    int   bi   = 64;               // sentinel, never survives (all v > -1)
    #pragma unroll
    for (int b = 0; b < 8; ++b) {
      bool ok = (((used >> b) & 1u) == 0u) && (v[b] > best);
      best = ok ? v[b] : best;
      bi   = ok ? (b * 8 + q) : bi;
    }
    #pragma unroll
    for (int m = 1; m <= 4; m <<= 1) {
      float ow = __shfl_xor(best, m, 64);
      int   oi = __shfl_xor(bi,   m, 64);
      bool take = (ow > best) || (ow == best && oi < bi);
      best = take ? ow : best;
      bi   = take ? oi : bi;
    }
    if ((bi & 7) == q) used |= (1u << (bi >> 3));   // owning lane retires it
    bool active = slot < dk;
    if (slot == q) {
      myw = active ? best : 0.f;
      myi = active ? (float)bi : 0.f;
    }
  }

  // wave writes 64 consecutive floats: tokens x slots, fully coalesced
  d_out[OFF_SELW + (size_t)tk * 8 + q] = myw;
  d_out[OFF_SELI + (size_t)tk * 8 + q] = myi;
  if (q == 0) d_out[OFF_CONF + tk] = (float)conf;
}

extern "C" void kernel_launch(void* const* d_in, const int* in_sizes, int n_in,
                              void* d_out, int out_size, void* d_ws, size_t ws_size,
                              hipStream_t stream) {
  const float* hidden   = (const float*)d_in[0];
  const float* W_router = (const float*)d_in[1];
  const float* b_router = (const float*)d_in[2];
  const float* W1       = (const float*)d_in[3];
  const float* b1       = (const float*)d_in[4];
  const float* W2       = (const float*)d_in[5];
  const float* b2       = (const float*)d_in[6];
  float* out = (float*)d_out;

  k_build<<<(HDIM * NOUT) / 256, 256, 0, stream>>>(W1, W_router);
  k_gemm<<<(N_TOK / BM) * 9, THREADS, 0, stream>>>(hidden, b1, W2, b_router,
                                                   out + OFF_LOG);
  k_post<<<N_TOK / 32, 256, 0, stream>>>(b2, out);
}